// Round 1
// baseline (686.449 us; speedup 1.0000x reference)
//
#include <hip/hip_runtime.h>

// Problem constants (from reference): B=4, L=1024, D=512, N=16, OUT=512, NL=2
#define BQ 4
#define LQ 1024
#define DQ 512
#define NQ 16
#define MQ (BQ*LQ)      // 4096 rows (b,l flattened)
#define CHUNK 32
#define NCH (LQ/CHUNK)  // 32 chunks

__device__ __forceinline__ float softplus_f(float x) {
    return (x > 20.0f) ? x : log1pf(__expf(x));
}

// ---------------------------------------------------------------------------
// fp32 tiled GEMM: C[M,N] = act(A[M,K] @ W[K,N] + bias[N])
// BM=64, BK=16, thread tile TM=4 x TN_. ACT_: 0=none, 1=softplus
// ---------------------------------------------------------------------------
template<int BN_, int TN_, int ACT_>
__global__ __launch_bounds__(256) void gemm_kernel(
    const float* __restrict__ Amat, const float* __restrict__ W,
    const float* __restrict__ bias, float* __restrict__ C,
    int M, int N, int K)
{
    const int BM = 64, BK = 16, TM = 4;
    __shared__ float As[BK][BM + 4];   // +4 pad keeps 16B alignment for b128 reads
    __shared__ float Ws[BK][BN_ + 4];
    int tid  = threadIdx.x;            // 256 threads
    int tcol = tid % (BN_ / TN_);
    int trow = tid / (BN_ / TN_);
    int bm = blockIdx.x * BM;
    int bn = blockIdx.y * BN_;
    float acc[TM][TN_];
    #pragma unroll
    for (int i = 0; i < TM; ++i)
        #pragma unroll
        for (int n = 0; n < TN_; ++n) acc[i][n] = 0.f;

    for (int k0 = 0; k0 < K; k0 += BK) {
        for (int l = tid; l < BM*BK; l += 256) {
            int i = l / BK, j = l % BK;
            As[j][i] = Amat[(size_t)(bm + i) * K + k0 + j];
        }
        for (int l = tid; l < BK*BN_; l += 256) {
            int j = l / BN_, n = l % BN_;
            Ws[j][n] = W[(size_t)(k0 + j) * N + bn + n];
        }
        __syncthreads();
        #pragma unroll
        for (int j = 0; j < BK; ++j) {
            float av[TM], wv[TN_];
            #pragma unroll
            for (int i = 0; i < TM; ++i) av[i] = As[j][trow*TM + i];
            #pragma unroll
            for (int n = 0; n < TN_; ++n) wv[n] = Ws[j][tcol*TN_ + n];
            #pragma unroll
            for (int i = 0; i < TM; ++i)
                #pragma unroll
                for (int n = 0; n < TN_; ++n)
                    acc[i][n] = fmaf(av[i], wv[n], acc[i][n]);
        }
        __syncthreads();
    }
    #pragma unroll
    for (int i = 0; i < TM; ++i) {
        int m = bm + trow*TM + i;
        #pragma unroll
        for (int n = 0; n < TN_; ++n) {
            int nn = bn + tcol*TN_ + n;
            float v = acc[i][n] + bias[nn];
            if (ACT_ == 1) v = softplus_f(v);
            C[(size_t)m * N + nn] = v;
        }
    }
}

// ---------------------------------------------------------------------------
// Scan phase 1: per (b, d, chunk) compute cumulative a-product and local h
// (zero-init) over the chunk. One thread per (b,d,chunk); N=16 state in regs.
// Writes summaries ap/hf at [((b*NCH+c)*D + d)*16 + n].
// ---------------------------------------------------------------------------
__global__ __launch_bounds__(256) void scan_phase1(
    const float* __restrict__ dt, const float* __restrict__ y,
    const float* __restrict__ Bm, const float* __restrict__ A,
    float* __restrict__ ap, float* __restrict__ hf)
{
    int idx  = blockIdx.x;          // B*NCH*(D/256) = 256 blocks
    int dblk = idx & 1;             // D/256 = 2
    int c    = (idx >> 1) & (NCH - 1);
    int b    = idx >> 6;            // 1 + 5
    int d    = dblk * 256 + threadIdx.x;

    float Ad[NQ];
    const float* Aptr = A + (size_t)d * NQ;
    #pragma unroll
    for (int n = 0; n < NQ; ++n) Ad[n] = Aptr[n];

    float h[NQ], prod[NQ];
    #pragma unroll
    for (int n = 0; n < NQ; ++n) { h[n] = 0.f; prod[n] = 1.f; }

    int t0 = c * CHUNK;
    const float* dtp = dt + ((size_t)b*LQ + t0) * DQ + d;
    const float* yp  = y  + ((size_t)b*LQ + t0) * DQ + d;
    const float* bp  = Bm + ((size_t)b*LQ + t0) * NQ;

    #pragma unroll 4
    for (int t = 0; t < CHUNK; ++t) {
        float dtv = dtp[(size_t)t * DQ];
        float yv  = yp[(size_t)t * DQ];
        float dty = dtv * yv;
        #pragma unroll
        for (int n = 0; n < NQ; ++n) {
            float a = __expf(dtv * Ad[n]);
            prod[n] *= a;
            h[n] = fmaf(a, h[n], dty * bp[t*NQ + n]);
        }
    }
    size_t base = ((size_t)(b*NCH + c) * DQ + d) * NQ;
    #pragma unroll
    for (int n = 0; n < NQ; n += 4) {
        *(float4*)(ap + base + n) = make_float4(prod[n], prod[n+1], prod[n+2], prod[n+3]);
        *(float4*)(hf + base + n) = make_float4(h[n], h[n+1], h[n+2], h[n+3]);
    }
}

// ---------------------------------------------------------------------------
// Scan phase 2: sequential scan over the NCH chunk summaries per (b,d,n).
// Writes h_init for each chunk IN PLACE over ap (read-before-write per idx).
// ---------------------------------------------------------------------------
__global__ __launch_bounds__(256) void scan_phase2(
    float* ap, const float* __restrict__ hf)
{
    int g = blockIdx.x * 256 + threadIdx.x;   // B*D*N = 32768 threads
    int n = g & (NQ - 1);
    int d = (g >> 4) & (DQ - 1);
    int b = g >> 13;
    float h = 0.f;
    for (int c = 0; c < NCH; ++c) {
        size_t idx = ((size_t)(b*NCH + c) * DQ + d) * NQ + n;
        float a = ap[idx];
        float f = hf[idx];
        ap[idx] = h;               // h_init for chunk c
        h = fmaf(a, h, f);
    }
}

// ---------------------------------------------------------------------------
// Scan phase 3: recompute local scan with correct h_init, emit
// yact = relu(sum_n h*Cm + Dskip*y). Writes IN PLACE over dt (per-thread
// read-before-write of the same element) -> dt/yact intentionally not restrict.
// ---------------------------------------------------------------------------
__global__ __launch_bounds__(256) void scan_phase3(
    const float* dt, const float* __restrict__ y,
    const float* __restrict__ Bm, const float* __restrict__ Cm,
    const float* __restrict__ A, const float* __restrict__ Dsk,
    const float* __restrict__ hi, float* yact)
{
    int idx  = blockIdx.x;
    int dblk = idx & 1;
    int c    = (idx >> 1) & (NCH - 1);
    int b    = idx >> 6;
    int d    = dblk * 256 + threadIdx.x;

    float Ad[NQ];
    const float* Aptr = A + (size_t)d * NQ;
    #pragma unroll
    for (int n = 0; n < NQ; ++n) Ad[n] = Aptr[n];

    float h[NQ];
    size_t base = ((size_t)(b*NCH + c) * DQ + d) * NQ;
    #pragma unroll
    for (int n = 0; n < NQ; n += 4) {
        float4 v = *(const float4*)(hi + base + n);
        h[n] = v.x; h[n+1] = v.y; h[n+2] = v.z; h[n+3] = v.w;
    }
    float dskip = Dsk[d];

    int t0 = c * CHUNK;
    const float* dtp = dt + ((size_t)b*LQ + t0) * DQ + d;
    const float* yp  = y  + ((size_t)b*LQ + t0) * DQ + d;
    const float* bp  = Bm + ((size_t)b*LQ + t0) * NQ;
    const float* cp  = Cm + ((size_t)b*LQ + t0) * NQ;
    float* op = yact + ((size_t)b*LQ + t0) * DQ + d;

    #pragma unroll 4
    for (int t = 0; t < CHUNK; ++t) {
        float dtv = dtp[(size_t)t * DQ];
        float yv  = yp[(size_t)t * DQ];
        float dty = dtv * yv;
        float acc = 0.f;
        #pragma unroll
        for (int n = 0; n < NQ; ++n) {
            float a = __expf(dtv * Ad[n]);
            h[n] = fmaf(a, h[n], dty * bp[t*NQ + n]);
            acc = fmaf(h[n], cp[t*NQ + n], acc);
        }
        float v = acc + dskip * yv;
        op[(size_t)t * DQ] = fmaxf(v, 0.f);
    }
}

// ---------------------------------------------------------------------------
extern "C" void kernel_launch(void* const* d_in, const int* in_sizes, int n_in,
                              void* d_out, int out_size, void* d_ws, size_t ws_size,
                              hipStream_t stream)
{
    const float* x    = (const float*)d_in[0];
    const float* A    = (const float*)d_in[1];
    const float* Dsk  = (const float*)d_in[2];
    const float* WB   = (const float*)d_in[3];
    const float* bB   = (const float*)d_in[4];
    const float* WC   = (const float*)d_in[5];
    const float* bC   = (const float*)d_in[6];
    const float* Wdt  = (const float*)d_in[7];
    const float* bdt  = (const float*)d_in[8];
    const float* Wlin = (const float*)d_in[9];
    const float* blin = (const float*)d_in[10];
    const float* Wdec = (const float*)d_in[11];
    const float* bdec = (const float*)d_in[12];
    float* out = (float*)d_out;

    // workspace layout (floats):
    float* ws   = (float*)d_ws;
    float* ybuf = ws;                          // MQ*DQ       = 2097152 (8MB)
    float* dtb  = ybuf + (size_t)MQ*DQ;        // MQ*DQ       = 2097152 (8MB)  (reused as yact)
    float* Bm   = dtb  + (size_t)MQ*DQ;        // MQ*NQ       = 65536
    float* Cm   = Bm   + (size_t)MQ*NQ;        // MQ*NQ       = 65536
    float* ap   = Cm   + (size_t)MQ*NQ;        // B*NCH*D*N   = 1048576 (4MB) (becomes h_init in phase2)
    float* hf   = ap   + (size_t)BQ*NCH*DQ*NQ; // B*NCH*D*N   = 1048576 (4MB)
    // total ~26 MB

    dim3 blk(256);
    for (int layer = 0; layer < 2; ++layer) {
        const float* yin = layer ? ybuf : x;
        // dt = softplus(y @ Wdt + bdt)
        gemm_kernel<64,4,1><<<dim3(MQ/64, DQ/64), blk, 0, stream>>>(
            yin, Wdt + (size_t)layer*DQ*DQ, bdt + (size_t)layer*DQ, dtb, MQ, DQ, DQ);
        // Bm = y @ WB + bB ; Cm = y @ WC + bC
        gemm_kernel<16,1,0><<<dim3(MQ/64, 1), blk, 0, stream>>>(
            yin, WB + (size_t)layer*DQ*NQ, bB + (size_t)layer*NQ, Bm, MQ, NQ, DQ);
        gemm_kernel<16,1,0><<<dim3(MQ/64, 1), blk, 0, stream>>>(
            yin, WC + (size_t)layer*DQ*NQ, bC + (size_t)layer*NQ, Cm, MQ, NQ, DQ);
        // chunked scan
        scan_phase1<<<dim3(BQ*NCH*(DQ/256)), blk, 0, stream>>>(
            dtb, yin, Bm, A + (size_t)layer*DQ*NQ, ap, hf);
        scan_phase2<<<dim3(BQ*DQ*NQ/256), blk, 0, stream>>>(ap, hf);
        scan_phase3<<<dim3(BQ*NCH*(DQ/256)), blk, 0, stream>>>(
            dtb, yin, Bm, Cm, A + (size_t)layer*DQ*NQ, Dsk + (size_t)layer*DQ,
            ap /*h_init*/, dtb /*in-place yact*/);
        // y = yact @ Wlin + blin
        gemm_kernel<64,4,0><<<dim3(MQ/64, DQ/64), blk, 0, stream>>>(
            dtb, Wlin + (size_t)layer*DQ*DQ, blin + (size_t)layer*DQ, ybuf, MQ, DQ, DQ);
    }
    // decoder
    gemm_kernel<64,4,0><<<dim3(MQ/64, DQ/64), blk, 0, stream>>>(
        ybuf, Wdec, bdec, out, MQ, DQ, DQ);
}

// Round 2
// 314.670 us; speedup vs baseline: 2.1815x; 2.1815x over previous
//
#include <hip/hip_runtime.h>

// Problem constants: B=4, L=1024, D=512, N=16, OUT=512, NL=2
#define BQ 4
#define LQ 1024
#define DQ 512
#define NQ 16
#define MQ (BQ*LQ)      // 4096 rows (b,l flattened)
#define CHUNK 32
#define NCH (LQ/CHUNK)  // 32 chunks
#define KQ 512          // GEMM K (== D)

typedef __bf16  bf16x8  __attribute__((ext_vector_type(8)));
typedef float   floatx4 __attribute__((ext_vector_type(4)));

__device__ __forceinline__ float softplus_f(float x) {
    return (x > 20.0f) ? x : log1pf(__expf(x));
}

// round-to-nearest-even fp32 -> bf16 (as ushort)
__device__ __forceinline__ unsigned short f2b(float f) {
    union { float f; unsigned u; } x; x.f = f;
    unsigned r = x.u + 0x7fffu + ((x.u >> 16) & 1u);
    return (unsigned short)(r >> 16);
}

__device__ __forceinline__ void load_lds16(const void* g, void* l) {
    __builtin_amdgcn_global_load_lds(
        (const __attribute__((address_space(1))) unsigned int*)g,
        (__attribute__((address_space(3))) unsigned int*)l,
        16, 0, 0);
}

// ---------------------------------------------------------------------------
// bf16 MFMA GEMM: C[M,N] = act(A[M,512] @ Wt[N,512]^T + bias)
// 64x64 tile, BK=32, 4 waves each 32x32 (2x2 of 16x16x32 MFMA).
// Wt is pre-transposed: Wt[n][k]. ACT_: 0=none, 1=softplus.
// WF32: write fp32 Cf. WBF16: write bf16 Cb.
// ---------------------------------------------------------------------------
template<int ACT_, bool WF32, bool WBF16>
__global__ __launch_bounds__(256) void gemm_mfma(
    const unsigned short* __restrict__ Abf,  // [M][512] bf16
    const unsigned short* __restrict__ Wt,   // [N][512] bf16 (transposed)
    const float* __restrict__ bias,          // [N]
    float* __restrict__ Cf,
    unsigned short* __restrict__ Cb,
    int M, int N)
{
    __shared__ __align__(16) unsigned short As[64 * 32];  // 4 KB
    __shared__ __align__(16) unsigned short Bs[64 * 32];  // 4 KB
    const int tid = threadIdx.x;
    const int wave = tid >> 6, lane = tid & 63;
    const int bm = blockIdx.x * 64, bn = blockIdx.y * 64;
    const int mw = (wave & 1) * 32, nw = (wave >> 1) * 32;

    // staging lane decomposition: 1-KB chunk = 16 rows of 32 bf16 (64 B)
    const int srow = lane >> 2;        // 0..15
    const int skof = (lane & 3) * 8;   // bf16 element offset (16 B granule)

    floatx4 acc[2][2];
    #pragma unroll
    for (int i = 0; i < 2; ++i)
        #pragma unroll
        for (int j = 0; j < 2; ++j)
            acc[i][j] = (floatx4){0.f, 0.f, 0.f, 0.f};

    const int r0 = wave * 16;  // this wave's 16-row chunk (for both A and B)
    for (int k0 = 0; k0 < KQ; k0 += 32) {
        __syncthreads();  // prior frag reads done before overwrite
        load_lds16(Abf + (size_t)(bm + r0 + srow) * KQ + k0 + skof, &As[r0 * 32]);
        load_lds16(Wt  + (size_t)(bn + r0 + srow) * KQ + k0 + skof, &Bs[r0 * 32]);
        __syncthreads();  // vmcnt(0) drain

        bf16x8 af[2], bfr[2];
        #pragma unroll
        for (int mt = 0; mt < 2; ++mt)
            af[mt] = *(const bf16x8*)&As[(mw + mt * 16 + (lane & 15)) * 32 + (lane >> 4) * 8];
        #pragma unroll
        for (int nt = 0; nt < 2; ++nt)
            bfr[nt] = *(const bf16x8*)&Bs[(nw + nt * 16 + (lane & 15)) * 32 + (lane >> 4) * 8];
        #pragma unroll
        for (int mt = 0; mt < 2; ++mt)
            #pragma unroll
            for (int nt = 0; nt < 2; ++nt)
                acc[mt][nt] = __builtin_amdgcn_mfma_f32_16x16x32_bf16(
                    af[mt], bfr[nt], acc[mt][nt], 0, 0, 0);
    }

    // epilogue: C/D layout col=lane&15, row=(lane>>4)*4+reg
    const int col0 = lane & 15, rquad = lane >> 4;
    #pragma unroll
    for (int mt = 0; mt < 2; ++mt) {
        #pragma unroll
        for (int nt = 0; nt < 2; ++nt) {
            int n = bn + nw + nt * 16 + col0;
            float bv = bias[n];
            #pragma unroll
            for (int r = 0; r < 4; ++r) {
                int m = bm + mw + mt * 16 + rquad * 4 + r;
                float v = acc[mt][nt][r] + bv;
                if (ACT_ == 1) v = softplus_f(v);
                if (WF32)  Cf[(size_t)m * N + n] = v;
                if (WBF16) Cb[(size_t)m * N + n] = f2b(v);
            }
        }
    }
}

// ---------------------------------------------------------------------------
// Fused B/C projection (fp32): Bm = y@WB + bB ; Cm = y@WC + bC. N=16 each.
// BM=32, BN=32 (16 B-cols + 16 C-cols), BK=16. grid = 128 blocks.
// ---------------------------------------------------------------------------
__global__ __launch_bounds__(256) void gemm_bc(
    const float* __restrict__ Y, const float* __restrict__ WB,
    const float* __restrict__ bB, const float* __restrict__ WC,
    const float* __restrict__ bC, float* __restrict__ Bm, float* __restrict__ Cm)
{
    __shared__ float Ys[16][33];
    __shared__ float Ws[16][33];
    int tid = threadIdx.x;
    int bm = blockIdx.x * 32;
    int trow = tid >> 4, tcol = tid & 15;
    float acc[2][2] = {{0.f, 0.f}, {0.f, 0.f}};

    for (int k0 = 0; k0 < KQ; k0 += 16) {
        for (int l = tid; l < 32 * 16; l += 256) {
            int i = l >> 4, j = l & 15;
            Ys[j][i] = Y[(size_t)(bm + i) * KQ + k0 + j];
        }
        for (int l = tid; l < 16 * 32; l += 256) {
            int j = l >> 5, n = l & 31;
            Ws[j][n] = (n < 16) ? WB[(size_t)(k0 + j) * NQ + n]
                                : WC[(size_t)(k0 + j) * NQ + n - 16];
        }
        __syncthreads();
        #pragma unroll
        for (int j = 0; j < 16; ++j) {
            float a0 = Ys[j][trow * 2], a1 = Ys[j][trow * 2 + 1];
            float w0 = Ws[j][tcol * 2], w1 = Ws[j][tcol * 2 + 1];
            acc[0][0] = fmaf(a0, w0, acc[0][0]);
            acc[0][1] = fmaf(a0, w1, acc[0][1]);
            acc[1][0] = fmaf(a1, w0, acc[1][0]);
            acc[1][1] = fmaf(a1, w1, acc[1][1]);
        }
        __syncthreads();
    }
    #pragma unroll
    for (int i = 0; i < 2; ++i) {
        int m = bm + trow * 2 + i;
        #pragma unroll
        for (int n = 0; n < 2; ++n) {
            int col = tcol * 2 + n;
            if (col < 16) Bm[(size_t)m * NQ + col]      = acc[i][n] + bB[col];
            else          Cm[(size_t)m * NQ + col - 16] = acc[i][n] + bC[col - 16];
        }
    }
}

// ---------------------------------------------------------------------------
// fp32 -> bf16 cast (4 elems/thread)
// ---------------------------------------------------------------------------
__global__ __launch_bounds__(256) void cast_bf16_kernel(
    const float* __restrict__ in, unsigned short* __restrict__ out)
{
    size_t i = ((size_t)blockIdx.x * 256 + threadIdx.x) * 4;
    float4 v = *(const float4*)(in + i);
    ushort4 o;
    o.x = f2b(v.x); o.y = f2b(v.y); o.z = f2b(v.z); o.w = f2b(v.w);
    *(ushort4*)(out + i) = o;
}

// ---------------------------------------------------------------------------
// transpose + cast: Wt[n][k] (bf16) = W[k][n] (fp32). 512x512 per z-slice.
// block (32,8), grid (16,16,nmat)
// ---------------------------------------------------------------------------
__global__ __launch_bounds__(256) void transpose_cast_kernel(
    const float* __restrict__ W, unsigned short* __restrict__ Wt)
{
    __shared__ float tile[32][33];
    int z = blockIdx.z;
    const float* Wm = W + (size_t)z * KQ * KQ;
    unsigned short* Wo = Wt + (size_t)z * KQ * KQ;
    int bx = blockIdx.x * 32, by = blockIdx.y * 32;  // bx: k-tile, by: n-tile
    int tx = threadIdx.x, ty = threadIdx.y;
    #pragma unroll
    for (int i = 0; i < 32; i += 8)
        tile[ty + i][tx] = Wm[(size_t)(bx + ty + i) * KQ + by + tx];  // tile[k][n]
    __syncthreads();
    #pragma unroll
    for (int i = 0; i < 32; i += 8)
        Wo[(size_t)(by + ty + i) * KQ + bx + tx] = f2b(tile[tx][ty + i]);
}

// ---------------------------------------------------------------------------
// Scan phase 1: per (b,d,chunk) cumulative a-product + local h (zero-init).
// ---------------------------------------------------------------------------
__global__ __launch_bounds__(256) void scan_phase1(
    const float* __restrict__ dt, const float* __restrict__ y,
    const float* __restrict__ Bm, const float* __restrict__ A,
    float* __restrict__ ap, float* __restrict__ hf)
{
    int idx  = blockIdx.x;
    int dblk = idx & 1;
    int c    = (idx >> 1) & (NCH - 1);
    int b    = idx >> 6;
    int d    = dblk * 256 + threadIdx.x;

    float Ad[NQ];
    const float* Aptr = A + (size_t)d * NQ;
    #pragma unroll
    for (int n = 0; n < NQ; ++n) Ad[n] = Aptr[n];

    float h[NQ], prod[NQ];
    #pragma unroll
    for (int n = 0; n < NQ; ++n) { h[n] = 0.f; prod[n] = 1.f; }

    int t0 = c * CHUNK;
    const float* dtp = dt + ((size_t)b*LQ + t0) * DQ + d;
    const float* yp  = y  + ((size_t)b*LQ + t0) * DQ + d;
    const float* bp  = Bm + ((size_t)b*LQ + t0) * NQ;

    #pragma unroll 4
    for (int t = 0; t < CHUNK; ++t) {
        float dtv = dtp[(size_t)t * DQ];
        float yv  = yp[(size_t)t * DQ];
        float dty = dtv * yv;
        #pragma unroll
        for (int n = 0; n < NQ; ++n) {
            float a = __expf(dtv * Ad[n]);
            prod[n] *= a;
            h[n] = fmaf(a, h[n], dty * bp[t*NQ + n]);
        }
    }
    size_t base = ((size_t)(b*NCH + c) * DQ + d) * NQ;
    #pragma unroll
    for (int n = 0; n < NQ; n += 4) {
        *(float4*)(ap + base + n) = make_float4(prod[n], prod[n+1], prod[n+2], prod[n+3]);
        *(float4*)(hf + base + n) = make_float4(h[n], h[n+1], h[n+2], h[n+3]);
    }
}

// ---------------------------------------------------------------------------
// Scan phase 2: sequential scan over NCH chunk summaries; h_init in-place.
// ---------------------------------------------------------------------------
__global__ __launch_bounds__(256) void scan_phase2(
    float* ap, const float* __restrict__ hf)
{
    int g = blockIdx.x * 256 + threadIdx.x;   // B*D*N threads
    int n = g & (NQ - 1);
    int d = (g >> 4) & (DQ - 1);
    int b = g >> 13;
    float h = 0.f;
    for (int c = 0; c < NCH; ++c) {
        size_t idx = ((size_t)(b*NCH + c) * DQ + d) * NQ + n;
        float a = ap[idx];
        float f = hf[idx];
        ap[idx] = h;
        h = fmaf(a, h, f);
    }
}

// ---------------------------------------------------------------------------
// Scan phase 3: recompute local scan with h_init, emit bf16
// yact = relu(sum_n h*Cm + Dskip*y)  (feeds the Wlin MFMA GEMM)
// ---------------------------------------------------------------------------
__global__ __launch_bounds__(256) void scan_phase3(
    const float* __restrict__ dt, const float* __restrict__ y,
    const float* __restrict__ Bm, const float* __restrict__ Cm,
    const float* __restrict__ A, const float* __restrict__ Dsk,
    const float* __restrict__ hi, unsigned short* __restrict__ yact)
{
    int idx  = blockIdx.x;
    int dblk = idx & 1;
    int c    = (idx >> 1) & (NCH - 1);
    int b    = idx >> 6;
    int d    = dblk * 256 + threadIdx.x;

    float Ad[NQ];
    const float* Aptr = A + (size_t)d * NQ;
    #pragma unroll
    for (int n = 0; n < NQ; ++n) Ad[n] = Aptr[n];

    float h[NQ];
    size_t base = ((size_t)(b*NCH + c) * DQ + d) * NQ;
    #pragma unroll
    for (int n = 0; n < NQ; n += 4) {
        float4 v = *(const float4*)(hi + base + n);
        h[n] = v.x; h[n+1] = v.y; h[n+2] = v.z; h[n+3] = v.w;
    }
    float dskip = Dsk[d];

    int t0 = c * CHUNK;
    const float* dtp = dt + ((size_t)b*LQ + t0) * DQ + d;
    const float* yp  = y  + ((size_t)b*LQ + t0) * DQ + d;
    const float* bp  = Bm + ((size_t)b*LQ + t0) * NQ;
    const float* cp  = Cm + ((size_t)b*LQ + t0) * NQ;
    unsigned short* op = yact + ((size_t)b*LQ + t0) * DQ + d;

    #pragma unroll 4
    for (int t = 0; t < CHUNK; ++t) {
        float dtv = dtp[(size_t)t * DQ];
        float yv  = yp[(size_t)t * DQ];
        float dty = dtv * yv;
        float acc = 0.f;
        #pragma unroll
        for (int n = 0; n < NQ; ++n) {
            float a = __expf(dtv * Ad[n]);
            h[n] = fmaf(a, h[n], dty * bp[t*NQ + n]);
            acc = fmaf(h[n], cp[t*NQ + n], acc);
        }
        float v = acc + dskip * yv;
        op[(size_t)t * DQ] = f2b(fmaxf(v, 0.f));
    }
}

// ---------------------------------------------------------------------------
extern "C" void kernel_launch(void* const* d_in, const int* in_sizes, int n_in,
                              void* d_out, int out_size, void* d_ws, size_t ws_size,
                              hipStream_t stream)
{
    const float* x    = (const float*)d_in[0];
    const float* A    = (const float*)d_in[1];
    const float* Dsk  = (const float*)d_in[2];
    const float* WB   = (const float*)d_in[3];
    const float* bB   = (const float*)d_in[4];
    const float* WC   = (const float*)d_in[5];
    const float* bC   = (const float*)d_in[6];
    const float* Wdt  = (const float*)d_in[7];
    const float* bdt  = (const float*)d_in[8];
    const float* Wlin = (const float*)d_in[9];
    const float* blin = (const float*)d_in[10];
    const float* Wdec = (const float*)d_in[11];
    const float* bdec = (const float*)d_in[12];
    float* out = (float*)d_out;

    // workspace layout
    char* cur = (char*)d_ws;
    float* ybuf = (float*)cur;           cur += (size_t)MQ*DQ*4;          // 8 MB
    float* dtb  = (float*)cur;           cur += (size_t)MQ*DQ*4;          // 8 MB
    float* Bm   = (float*)cur;           cur += (size_t)MQ*NQ*4;
    float* Cm   = (float*)cur;           cur += (size_t)MQ*NQ*4;
    float* ap   = (float*)cur;           cur += (size_t)BQ*NCH*DQ*NQ*4;   // 4 MB
    float* hf   = (float*)cur;           cur += (size_t)BQ*NCH*DQ*NQ*4;   // 4 MB
    unsigned short* y16    = (unsigned short*)cur; cur += (size_t)MQ*DQ*2;  // 4 MB
    unsigned short* yact16 = (unsigned short*)cur; cur += (size_t)MQ*DQ*2;  // 4 MB
    unsigned short* Wt     = (unsigned short*)cur; cur += (size_t)5*KQ*KQ*2; // 2.5 MB
    unsigned short* Wt_dt  = Wt;                    // [2][512][512]
    unsigned short* Wt_lin = Wt + (size_t)2*KQ*KQ;  // [2][512][512]
    unsigned short* Wt_dec = Wt + (size_t)4*KQ*KQ;  // [512][512]

    dim3 blk(256);
    dim3 blkT(32, 8);

    // weight transpose+cast (runs every call; weights are re-poisoned/restored)
    transpose_cast_kernel<<<dim3(16,16,2), blkT, 0, stream>>>(Wdt,  Wt_dt);
    transpose_cast_kernel<<<dim3(16,16,2), blkT, 0, stream>>>(Wlin, Wt_lin);
    transpose_cast_kernel<<<dim3(16,16,1), blkT, 0, stream>>>(Wdec, Wt_dec);
    // x -> bf16
    cast_bf16_kernel<<<dim3(MQ*DQ/1024), blk, 0, stream>>>(x, y16);

    dim3 gGemm(MQ/64, DQ/64);   // 64 x 8 = 512 blocks
    for (int layer = 0; layer < 2; ++layer) {
        const float* yin = layer ? ybuf : x;
        // dt = softplus(y @ Wdt + bdt)   [bf16 MFMA, fp32 out]
        gemm_mfma<1, true, false><<<gGemm, blk, 0, stream>>>(
            y16, Wt_dt + (size_t)layer*KQ*KQ, bdt + (size_t)layer*DQ,
            dtb, (unsigned short*)nullptr, MQ, DQ);
        // Bm, Cm (fused fp32)
        gemm_bc<<<dim3(MQ/32), blk, 0, stream>>>(yin, WB + (size_t)layer*DQ*NQ,
            bB + (size_t)layer*NQ, WC + (size_t)layer*DQ*NQ, bC + (size_t)layer*NQ,
            Bm, Cm);
        // chunked scan
        scan_phase1<<<dim3(BQ*NCH*(DQ/256)), blk, 0, stream>>>(
            dtb, yin, Bm, A + (size_t)layer*DQ*NQ, ap, hf);
        scan_phase2<<<dim3(BQ*DQ*NQ/256), blk, 0, stream>>>(ap, hf);
        scan_phase3<<<dim3(BQ*NCH*(DQ/256)), blk, 0, stream>>>(
            dtb, yin, Bm, Cm, A + (size_t)layer*DQ*NQ, Dsk + (size_t)layer*DQ,
            ap, yact16);
        // y = yact @ Wlin + blin  [bf16 MFMA, fp32 + bf16 out]
        gemm_mfma<0, true, true><<<gGemm, blk, 0, stream>>>(
            yact16, Wt_lin + (size_t)layer*KQ*KQ, blin + (size_t)layer*DQ,
            ybuf, y16, MQ, DQ);
    }
    // decoder (reads y16 written by layer-1 Wlin epilogue)
    gemm_mfma<0, true, false><<<gGemm, blk, 0, stream>>>(
        y16, Wt_dec, bdec, out, (unsigned short*)nullptr, MQ, DQ);
}

// Round 3
// 251.314 us; speedup vs baseline: 2.7314x; 1.2521x over previous
//
#include <hip/hip_runtime.h>

// Problem constants: B=4, L=1024, D=512, N=16, OUT=512, NL=2
#define BQ 4
#define LQ 1024
#define DQ 512
#define NQ 16
#define MQ (BQ*LQ)      // 4096 rows (b,l flattened)
#define CHUNK 32
#define NCH (LQ/CHUNK)  // 32 chunks
#define KQ 512          // GEMM K (== D)
#define NFUSE 576       // 512 dt + 16 B + 16 C + 32 pad

typedef __bf16  bf16x8  __attribute__((ext_vector_type(8)));
typedef float   floatx4 __attribute__((ext_vector_type(4)));

__device__ __forceinline__ float softplus_f(float x) {
    return (x > 20.0f) ? x : log1pf(__expf(x));
}

// round-to-nearest-even fp32 -> bf16 (as ushort)
__device__ __forceinline__ unsigned short f2b(float f) {
    union { float f; unsigned u; } x; x.f = f;
    unsigned r = x.u + 0x7fffu + ((x.u >> 16) & 1u);
    return (unsigned short)(r >> 16);
}

__device__ __forceinline__ void load_lds16(const void* g, void* l) {
    __builtin_amdgcn_global_load_lds(
        (const __attribute__((address_space(1))) unsigned int*)g,
        (__attribute__((address_space(3))) unsigned int*)l,
        16, 0, 0);
}

// ===========================================================================
// MFMA GEMM core: 128x64 block tile, BK=32, 4 waves, wave tile 64x32 (4x2 of
// 16x16x32 MFMA). A[M][512] bf16, Wt[N][512] bf16 (pre-transposed).
// ===========================================================================
#define GEMM_CORE_BODY                                                        \
    __shared__ __align__(16) unsigned short As[128 * 32];  /* 8 KB */         \
    __shared__ __align__(16) unsigned short Bs[64 * 32];   /* 4 KB */         \
    const int tid = threadIdx.x;                                              \
    const int wave = tid >> 6, lane = tid & 63;                               \
    const int bm = blockIdx.x * 128, bn = blockIdx.y * 64;                    \
    const int mw = (wave & 1) * 64, nw = (wave >> 1) * 32;                    \
    const int srow = lane >> 2;                                               \
    const int sg   = (lane & 3) * 8;                                          \
    floatx4 acc[4][2];                                                        \
    _Pragma("unroll")                                                         \
    for (int i = 0; i < 4; ++i)                                               \
        _Pragma("unroll")                                                     \
        for (int j = 0; j < 2; ++j) acc[i][j] = (floatx4){0.f,0.f,0.f,0.f};   \
    for (int k0 = 0; k0 < KQ; k0 += 32) {                                     \
        __syncthreads();                                                      \
        {                                                                     \
            int R = wave * 32;                                                \
            load_lds16(Abf + (size_t)(bm + R + srow) * KQ + k0 + sg,          \
                       &As[R * 32]);                                          \
            load_lds16(Abf + (size_t)(bm + R + 16 + srow) * KQ + k0 + sg,     \
                       &As[(R + 16) * 32]);                                   \
            load_lds16(Wt + (size_t)(bn + wave * 16 + srow) * KQ + k0 + sg,   \
                       &Bs[wave * 16 * 32]);                                  \
        }                                                                     \
        __syncthreads();                                                      \
        bf16x8 af[4], bfr[2];                                                 \
        _Pragma("unroll")                                                     \
        for (int mt = 0; mt < 4; ++mt)                                        \
            af[mt] = *(const bf16x8*)                                         \
                &As[(mw + mt*16 + (lane & 15)) * 32 + (lane >> 4) * 8];       \
        _Pragma("unroll")                                                     \
        for (int nt = 0; nt < 2; ++nt)                                        \
            bfr[nt] = *(const bf16x8*)                                        \
                &Bs[(nw + nt*16 + (lane & 15)) * 32 + (lane >> 4) * 8];       \
        _Pragma("unroll")                                                     \
        for (int mt = 0; mt < 4; ++mt)                                        \
            _Pragma("unroll")                                                 \
            for (int nt = 0; nt < 2; ++nt)                                    \
                acc[mt][nt] = __builtin_amdgcn_mfma_f32_16x16x32_bf16(        \
                    af[mt], bfr[nt], acc[mt][nt], 0, 0, 0);                   \
    }                                                                         \
    const int col0 = lane & 15, rq = lane >> 4;

// ---------------------------------------------------------------------------
// Plain GEMM: Cf[M][N] = A@Wt^T + bias; optional bf16 dual write.
// ---------------------------------------------------------------------------
template<bool WBF16>
__global__ __launch_bounds__(256) void gemm_out(
    const unsigned short* __restrict__ Abf,
    const unsigned short* __restrict__ Wt,
    const float* __restrict__ bias,
    float* __restrict__ Cf, unsigned short* __restrict__ Cb, int N)
{
    GEMM_CORE_BODY
    #pragma unroll
    for (int mt = 0; mt < 4; ++mt) {
        #pragma unroll
        for (int nt = 0; nt < 2; ++nt) {
            int n = bn + nw + nt * 16 + col0;
            float bv = bias[n];
            #pragma unroll
            for (int r = 0; r < 4; ++r) {
                int m = bm + mw + mt * 16 + rq * 4 + r;
                float v = acc[mt][nt][r] + bv;
                Cf[(size_t)m * N + n] = v;
                if (WBF16) Cb[(size_t)m * N + n] = f2b(v);
            }
        }
    }
}

// ---------------------------------------------------------------------------
// Fused dt/B/C GEMM: Wt is [576][512]: rows 0-511 Wdt^T, 512-527 WB^T,
// 528-543 WC^T, 544-575 zero. Epilogue routes per 16-col tile.
// ---------------------------------------------------------------------------
__global__ __launch_bounds__(256) void gemm_fused(
    const unsigned short* __restrict__ Abf,
    const unsigned short* __restrict__ Wt,
    const float* __restrict__ bdt, const float* __restrict__ bB,
    const float* __restrict__ bC,
    float* __restrict__ dtb, float* __restrict__ Bm, float* __restrict__ Cm)
{
    GEMM_CORE_BODY
    #pragma unroll
    for (int mt = 0; mt < 4; ++mt) {
        #pragma unroll
        for (int nt = 0; nt < 2; ++nt) {
            int nb = bn + nw + nt * 16;    // tile-uniform region selector
            int n  = nb + col0;
            if (nb < 512) {
                float bv = bdt[n];
                #pragma unroll
                for (int r = 0; r < 4; ++r) {
                    int m = bm + mw + mt * 16 + rq * 4 + r;
                    dtb[(size_t)m * DQ + n] = softplus_f(acc[mt][nt][r] + bv);
                }
            } else if (nb < 528) {
                float bv = bB[n - 512];
                #pragma unroll
                for (int r = 0; r < 4; ++r) {
                    int m = bm + mw + mt * 16 + rq * 4 + r;
                    Bm[(size_t)m * NQ + (n - 512)] = acc[mt][nt][r] + bv;
                }
            } else if (nb < 544) {
                float bv = bC[n - 528];
                #pragma unroll
                for (int r = 0; r < 4; ++r) {
                    int m = bm + mw + mt * 16 + rq * 4 + r;
                    Cm[(size_t)m * NQ + (n - 528)] = acc[mt][nt][r] + bv;
                }
            }
        }
    }
}

// ---------------------------------------------------------------------------
// fp32 -> bf16 cast (4 elems/thread)
// ---------------------------------------------------------------------------
__global__ __launch_bounds__(256) void cast_bf16_kernel(
    const float* __restrict__ in, unsigned short* __restrict__ out)
{
    size_t i = ((size_t)blockIdx.x * 256 + threadIdx.x) * 4;
    float4 v = *(const float4*)(in + i);
    ushort4 o;
    o.x = f2b(v.x); o.y = f2b(v.y); o.z = f2b(v.z); o.w = f2b(v.w);
    *(ushort4*)(out + i) = o;
}

// ---------------------------------------------------------------------------
// transpose + cast: Wt[n][k] (bf16, pitch 512) = W[k][n] (fp32) per z-slice.
// ---------------------------------------------------------------------------
__global__ __launch_bounds__(256) void transpose_cast_kernel(
    const float* __restrict__ W, unsigned short* __restrict__ Wt,
    size_t in_stride, size_t out_stride)
{
    __shared__ float tile[32][33];
    int z = blockIdx.z;
    const float* Wm = W + (size_t)z * in_stride;
    unsigned short* Wo = Wt + (size_t)z * out_stride;
    int bx = blockIdx.x * 32, by = blockIdx.y * 32;
    int tx = threadIdx.x, ty = threadIdx.y;
    #pragma unroll
    for (int i = 0; i < 32; i += 8)
        tile[ty + i][tx] = Wm[(size_t)(bx + ty + i) * KQ + by + tx];
    __syncthreads();
    #pragma unroll
    for (int i = 0; i < 32; i += 8)
        Wo[(size_t)(by + ty + i) * KQ + bx + tx] = f2b(tile[tx][ty + i]);
}

// ---------------------------------------------------------------------------
// pack WB/WC transposed (bf16) into rows 512..575 of the fused weight matrix.
// grid (64, NL): blockIdx.x = row within region, blockIdx.y = layer.
// ---------------------------------------------------------------------------
__global__ __launch_bounds__(256) void pack_bc_kernel(
    const float* __restrict__ WB, const float* __restrict__ WC,
    unsigned short* __restrict__ Wf)
{
    int r = blockIdx.x;            // 0..63
    int layer = blockIdx.y;
    unsigned short* dst = Wf + (size_t)layer * NFUSE * KQ + (size_t)(512 + r) * KQ;
    const float* src = nullptr;
    int n = 0;
    if (r < 16)      { src = WB + (size_t)layer * DQ * NQ; n = r; }
    else if (r < 32) { src = WC + (size_t)layer * DQ * NQ; n = r - 16; }
    for (int k = threadIdx.x; k < KQ; k += 256)
        dst[k] = src ? f2b(src[(size_t)k * NQ + n]) : (unsigned short)0;
}

// ---------------------------------------------------------------------------
// Scan phase 1: per (b,d,chunk) cumulative a-product + local h (zero-init).
// ---------------------------------------------------------------------------
__global__ __launch_bounds__(256) void scan_phase1(
    const float* __restrict__ dt, const float* __restrict__ y,
    const float* __restrict__ Bm, const float* __restrict__ A,
    float* __restrict__ ap, float* __restrict__ hf)
{
    int idx  = blockIdx.x;
    int dblk = idx & 1;
    int c    = (idx >> 1) & (NCH - 1);
    int b    = idx >> 6;
    int d    = dblk * 256 + threadIdx.x;

    float Ad[NQ];
    const float* Aptr = A + (size_t)d * NQ;
    #pragma unroll
    for (int n = 0; n < NQ; ++n) Ad[n] = Aptr[n];

    float h[NQ], prod[NQ];
    #pragma unroll
    for (int n = 0; n < NQ; ++n) { h[n] = 0.f; prod[n] = 1.f; }

    int t0 = c * CHUNK;
    const float* dtp = dt + ((size_t)b*LQ + t0) * DQ + d;
    const float* yp  = y  + ((size_t)b*LQ + t0) * DQ + d;
    const float* bp  = Bm + ((size_t)b*LQ + t0) * NQ;

    #pragma unroll 4
    for (int t = 0; t < CHUNK; ++t) {
        float dtv = dtp[(size_t)t * DQ];
        float yv  = yp[(size_t)t * DQ];
        float dty = dtv * yv;
        #pragma unroll
        for (int n = 0; n < NQ; ++n) {
            float a = __expf(dtv * Ad[n]);
            prod[n] *= a;
            h[n] = fmaf(a, h[n], dty * bp[t*NQ + n]);
        }
    }
    size_t base = ((size_t)(b*NCH + c) * DQ + d) * NQ;
    #pragma unroll
    for (int n = 0; n < NQ; n += 4) {
        *(float4*)(ap + base + n) = make_float4(prod[n], prod[n+1], prod[n+2], prod[n+3]);
        *(float4*)(hf + base + n) = make_float4(h[n], h[n+1], h[n+2], h[n+3]);
    }
}

// ---------------------------------------------------------------------------
// Scan phase 2: sequential scan over NCH chunk summaries; h_init in-place.
// ---------------------------------------------------------------------------
__global__ __launch_bounds__(256) void scan_phase2(
    float* ap, const float* __restrict__ hf)
{
    int g = blockIdx.x * 256 + threadIdx.x;   // B*D*N threads
    int n = g & (NQ - 1);
    int d = (g >> 4) & (DQ - 1);
    int b = g >> 13;
    float h = 0.f;
    for (int c = 0; c < NCH; ++c) {
        size_t idx = ((size_t)(b*NCH + c) * DQ + d) * NQ + n;
        float a = ap[idx];
        float f = hf[idx];
        ap[idx] = h;
        h = fmaf(a, h, f);
    }
}

// ---------------------------------------------------------------------------
// Scan phase 3: recompute local scan with h_init, emit bf16
// yact = relu(sum_n h*Cm + Dskip*y)
// ---------------------------------------------------------------------------
__global__ __launch_bounds__(256) void scan_phase3(
    const float* __restrict__ dt, const float* __restrict__ y,
    const float* __restrict__ Bm, const float* __restrict__ Cm,
    const float* __restrict__ A, const float* __restrict__ Dsk,
    const float* __restrict__ hi, unsigned short* __restrict__ yact)
{
    int idx  = blockIdx.x;
    int dblk = idx & 1;
    int c    = (idx >> 1) & (NCH - 1);
    int b    = idx >> 6;
    int d    = dblk * 256 + threadIdx.x;

    float Ad[NQ];
    const float* Aptr = A + (size_t)d * NQ;
    #pragma unroll
    for (int n = 0; n < NQ; ++n) Ad[n] = Aptr[n];

    float h[NQ];
    size_t base = ((size_t)(b*NCH + c) * DQ + d) * NQ;
    #pragma unroll
    for (int n = 0; n < NQ; n += 4) {
        float4 v = *(const float4*)(hi + base + n);
        h[n] = v.x; h[n+1] = v.y; h[n+2] = v.z; h[n+3] = v.w;
    }
    float dskip = Dsk[d];

    int t0 = c * CHUNK;
    const float* dtp = dt + ((size_t)b*LQ + t0) * DQ + d;
    const float* yp  = y  + ((size_t)b*LQ + t0) * DQ + d;
    const float* bp  = Bm + ((size_t)b*LQ + t0) * NQ;
    const float* cp  = Cm + ((size_t)b*LQ + t0) * NQ;
    unsigned short* op = yact + ((size_t)b*LQ + t0) * DQ + d;

    #pragma unroll 4
    for (int t = 0; t < CHUNK; ++t) {
        float dtv = dtp[(size_t)t * DQ];
        float yv  = yp[(size_t)t * DQ];
        float dty = dtv * yv;
        float acc = 0.f;
        #pragma unroll
        for (int n = 0; n < NQ; ++n) {
            float a = __expf(dtv * Ad[n]);
            h[n] = fmaf(a, h[n], dty * bp[t*NQ + n]);
            acc = fmaf(h[n], cp[t*NQ + n], acc);
        }
        float v = acc + dskip * yv;
        op[(size_t)t * DQ] = f2b(fmaxf(v, 0.f));
    }
}

// ---------------------------------------------------------------------------
extern "C" void kernel_launch(void* const* d_in, const int* in_sizes, int n_in,
                              void* d_out, int out_size, void* d_ws, size_t ws_size,
                              hipStream_t stream)
{
    const float* x    = (const float*)d_in[0];
    const float* A    = (const float*)d_in[1];
    const float* Dsk  = (const float*)d_in[2];
    const float* WB   = (const float*)d_in[3];
    const float* bB   = (const float*)d_in[4];
    const float* WC   = (const float*)d_in[5];
    const float* bC   = (const float*)d_in[6];
    const float* Wdt  = (const float*)d_in[7];
    const float* bdt  = (const float*)d_in[8];
    const float* Wlin = (const float*)d_in[9];
    const float* blin = (const float*)d_in[10];
    const float* Wdec = (const float*)d_in[11];
    const float* bdec = (const float*)d_in[12];
    float* out = (float*)d_out;

    // workspace layout
    char* cur = (char*)d_ws;
    float* ybuf = (float*)cur;           cur += (size_t)MQ*DQ*4;          // 8 MB
    float* dtb  = (float*)cur;           cur += (size_t)MQ*DQ*4;          // 8 MB
    float* Bm   = (float*)cur;           cur += (size_t)MQ*NQ*4;
    float* Cm   = (float*)cur;           cur += (size_t)MQ*NQ*4;
    float* ap   = (float*)cur;           cur += (size_t)BQ*NCH*DQ*NQ*4;   // 4 MB
    float* hf   = (float*)cur;           cur += (size_t)BQ*NCH*DQ*NQ*4;   // 4 MB
    unsigned short* y16    = (unsigned short*)cur; cur += (size_t)MQ*DQ*2;   // 4 MB
    unsigned short* yact16 = (unsigned short*)cur; cur += (size_t)MQ*DQ*2;   // 4 MB
    unsigned short* Wf     = (unsigned short*)cur; cur += (size_t)2*NFUSE*KQ*2; // 1.125 MB
    unsigned short* Wt_lin = (unsigned short*)cur; cur += (size_t)2*KQ*KQ*2;   // 1 MB
    unsigned short* Wt_dec = (unsigned short*)cur; cur += (size_t)KQ*KQ*2;     // 0.5 MB

    dim3 blk(256);
    dim3 blkT(32, 8);

    // weight prep (every call; inputs restored before each timed launch)
    transpose_cast_kernel<<<dim3(16,16,1), blkT, 0, stream>>>(
        Wdt, Wf, 0, 0);
    transpose_cast_kernel<<<dim3(16,16,1), blkT, 0, stream>>>(
        Wdt + (size_t)KQ*KQ, Wf + (size_t)NFUSE*KQ, 0, 0);
    transpose_cast_kernel<<<dim3(16,16,2), blkT, 0, stream>>>(
        Wlin, Wt_lin, (size_t)KQ*KQ, (size_t)KQ*KQ);
    transpose_cast_kernel<<<dim3(16,16,1), blkT, 0, stream>>>(
        Wdec, Wt_dec, 0, 0);
    pack_bc_kernel<<<dim3(64, 2), blk, 0, stream>>>(WB, WC, Wf);
    cast_bf16_kernel<<<dim3(MQ*DQ/1024), blk, 0, stream>>>(x, y16);

    dim3 gFused(MQ/128, NFUSE/64);   // 32 x 9
    dim3 gOut(MQ/128, DQ/64);        // 32 x 8
    for (int layer = 0; layer < 2; ++layer) {
        const float* yin = layer ? ybuf : x;
        // dt (softplus) + Bm + Cm in one MFMA GEMM
        gemm_fused<<<gFused, blk, 0, stream>>>(
            y16, Wf + (size_t)layer*NFUSE*KQ,
            bdt + (size_t)layer*DQ, bB + (size_t)layer*NQ, bC + (size_t)layer*NQ,
            dtb, Bm, Cm);
        // chunked scan
        scan_phase1<<<dim3(BQ*NCH*(DQ/256)), blk, 0, stream>>>(
            dtb, yin, Bm, A + (size_t)layer*DQ*NQ, ap, hf);
        scan_phase2<<<dim3(BQ*DQ*NQ/256), blk, 0, stream>>>(ap, hf);
        scan_phase3<<<dim3(BQ*NCH*(DQ/256)), blk, 0, stream>>>(
            dtb, yin, Bm, Cm, A + (size_t)layer*DQ*NQ, Dsk + (size_t)layer*DQ,
            ap, yact16);
        // y = yact @ Wlin + blin  (fp32 for scan + bf16 for next GEMM)
        gemm_out<true><<<gOut, blk, 0, stream>>>(
            yact16, Wt_lin + (size_t)layer*KQ*KQ, blin + (size_t)layer*DQ,
            ybuf, y16, DQ);
    }
    // decoder
    gemm_out<false><<<gOut, blk, 0, stream>>>(
        y16, Wt_dec, bdec, out, (unsigned short*)nullptr, DQ);
}